// Round 16
// baseline (815.764 us; speedup 1.0000x reference)
//
#include <hip/hip_runtime.h>
#include <hip/hip_bf16.h>
#include <math.h>

using short8  = __attribute__((ext_vector_type(8))) short;
using ushort8v = __attribute__((ext_vector_type(8))) unsigned short;
using f32x4   = __attribute__((ext_vector_type(4))) float;

// ---------- helpers ----------
__device__ __forceinline__ float bf2f(unsigned short u) {
    return __uint_as_float(((unsigned int)u) << 16);
}
__device__ __forceinline__ unsigned short f2bf(float f) {
    unsigned int x = __float_as_uint(f);
    return (unsigned short)((x + 0x7fffu + ((x >> 16) & 1u)) >> 16);
}
// async global->LDS, 16B per lane; LDS dest is wave-uniform base + lane*16
__device__ __forceinline__ void gll16(const void* g, void* l) {
    __builtin_amdgcn_global_load_lds(
        (const __attribute__((address_space(1))) unsigned int*)g,
        (__attribute__((address_space(3))) unsigned int*)l, 16, 0, 0);
}

// ---------- fused per-edge-type projection weights, written transposed bf16 ----------
// wt slots (rows of [2560][256]): 0 Wq0 | 1 e0k | 2 e0v | 3 Wq1 | 4 e1k | 5 e1v
//                                 | 6 e2k | 7 e2v | 8 Wfc0 | 9 Wfc1
__global__ __launch_bounds__(256) void build_eff_t(
    const float* __restrict__ Wk, const float* __restrict__ Wv,
    const float* __restrict__ att_w, const float* __restrict__ val_w,
    unsigned short* __restrict__ wt)
{
    int gid = blockIdx.x;          // mat*256 + c
    int mat = gid >> 8, c = gid & 255;   // mat: e*2 + (0=k,1=v)
    int e = mat >> 1, which = mat & 1;
    int ts = (e == 0) ? 0 : 1;
    int h = c >> 5, j = c & 31;
    int k = threadIdx.x;
    const float* Wsrc = (which == 0 ? Wk : Wv) + ((size_t)ts * 256 + k) * 256 + h * 32;
    const float* aw = (which == 0 ? att_w : val_w) + (size_t)((e * 8 + h) * 32) * 32 + j;
    float s = 0.f;
    #pragma unroll
    for (int d = 0; d < 32; ++d) s += Wsrc[d] * aw[d * 32];
    int slot = mat < 2 ? mat + 1 : mat + 2;
    wt[((size_t)slot * 256 + c) * 256 + k] = f2bf(s);
}

__global__ void build_eff_bias(
    const float* __restrict__ bk, const float* __restrict__ bv,
    const float* __restrict__ att_w, const float* __restrict__ val_w,
    float* __restrict__ effb)
{
    int mat = blockIdx.x;          // 0..5
    int c = threadIdx.x;
    int e = mat >> 1, which = mat & 1;
    int ts = (e == 0) ? 0 : 1;
    int h = c >> 5, j = c & 31;
    const float* bsrc = (which == 0 ? bk : bv) + ts * 256 + h * 32;
    const float* aw = (which == 0 ? att_w : val_w) + (size_t)((e * 8 + h) * 32) * 32 + j;
    float s = 0.f;
    #pragma unroll
    for (int d = 0; d < 32; ++d) s += bsrc[d] * aw[d * 32];
    effb[mat * 256 + c] = s;
}

// bias_cat[2048]: [bq0|e0k|e0v]  [bq1|e1k|e1v|e2k|e2v]
__global__ void build_bias_cat(const float* __restrict__ bq,
                               const float* __restrict__ effb,
                               float* __restrict__ bc)
{
    int i = blockIdx.x * 256 + threadIdx.x;
    int seg = i >> 8, o = i & 255;
    float v;
    switch (seg) {
        case 0: v = bq[o]; break;
        case 1: v = effb[o]; break;
        case 2: v = effb[256 + o]; break;
        case 3: v = bq[256 + o]; break;
        case 4: v = effb[512 + o]; break;
        case 5: v = effb[768 + o]; break;
        case 6: v = effb[1024 + o]; break;
        default: v = effb[1280 + o]; break;
    }
    bc[i] = v;
}

// transpose+cast Wq0, Wq1, Wfc0, Wfc1 into wt slots 0,3,8,9
__global__ __launch_bounds__(256) void transpose_cast4(
    const float* __restrict__ Wq, const float* __restrict__ Wfc,
    unsigned short* __restrict__ wt)
{
    __shared__ float tile[32][33];
    int mi = blockIdx.x >> 6;
    int bid = blockIdx.x & 63;
    const float* src; int slot;
    switch (mi) {
        case 0: src = Wq;           slot = 0; break;
        case 1: src = Wq + 65536;   slot = 3; break;
        case 2: src = Wfc;          slot = 8; break;
        default: src = Wfc + 65536; slot = 9; break;
    }
    unsigned short* dst = wt + (size_t)slot * 65536;
    int bx = bid & 7, by = bid >> 3;
    int tx = threadIdx.x & 31, ty = threadIdx.x >> 5;
    #pragma unroll
    for (int i = 0; i < 4; ++i)
        tile[ty + i * 8][tx] = src[(size_t)(by * 32 + ty + i * 8) * 256 + bx * 32 + tx];
    __syncthreads();
    #pragma unroll
    for (int i = 0; i < 4; ++i)
        dst[(size_t)(bx * 32 + ty + i * 8) * 256 + by * 32 + tx] = f2bf(tile[tx][ty + i * 8]);
}

// cast both feature matrices in one dispatch
__global__ void cast_bf16_2(const float* __restrict__ a, const float* __restrict__ b,
                            unsigned short* __restrict__ oa, unsigned short* __restrict__ ob,
                            int n4a, int n4b)
{
    int i = blockIdx.x * 256 + threadIdx.x;
    if (i < n4a) {
        float4 v = ((const float4*)a)[i];
        ushort4 o; o.x = f2bf(v.x); o.y = f2bf(v.y); o.z = f2bf(v.z); o.w = f2bf(v.w);
        ((ushort4*)oa)[i] = o;
    } else if (i - n4a < n4b) {
        int j = i - n4a;
        float4 v = ((const float4*)b)[j];
        ushort4 o; o.x = f2bf(v.x); o.y = f2bf(v.y); o.z = f2bf(v.z); o.w = f2bf(v.w);
        ((ushort4*)ob)[j] = o;
    }
}

// ======================================================================
// Input-side GEMM: C[M][Ncat] = A[M][256](bf16) @ Wt_seg (+bias).
// Tile 128x256, 512 thr / 8 waves (K-loop mirrors gemm_ln2's proven loop),
// BK=32, dbuf global_load_lds(16B), both-sides XOR swizzle.
// 1D grid + bijective XCD-chunk swizzle; col-siblings share A-tile in L2.
// Epilogue: acc(+bias) -> 64KB LDS stage (granule swizzle) -> 16B stores.
// ======================================================================
__global__ __launch_bounds__(512, 2) void gemm_cat(
    const unsigned short* __restrict__ A, const unsigned short* __restrict__ Wt,
    const float* __restrict__ bias, unsigned short* __restrict__ C,
    int M, int Ncat, int ncols, int nwg)
{
    __shared__ unsigned short sh[32768];   // K-loop: As[2][4096] @0 | Bs[2][8192] @8192; epilogue: 128x256
    int orig = blockIdx.x;
    int q = nwg >> 3, r = nwg & 7;
    int xcd = orig & 7;
    int wgid = (xcd < r ? xcd * (q + 1) : r * (q + 1) + (xcd - r) * q) + (orig >> 3);
    int m0 = (wgid / ncols) * 128;
    int n0 = (wgid % ncols) * 256;

    int t = threadIdx.x, w = t >> 6, l = t & 63;
    int lr = l & 15, lg = l >> 4;
    int wr = w >> 1, wc = w & 1;        // 4 row-groups x 2 col-halves

    int lrow = l >> 2, lq = l & 3;
    int qsw = lq ^ ((lrow >> 1) & 3);
    int ar = m0 + w * 16 + lrow; if (ar >= M) ar = M - 1;
    const unsigned short* Apt = A  + (size_t)ar * 256 + qsw * 8;
    const unsigned short* Bp0 = Wt + (size_t)(n0 + w * 16 + lrow) * 256 + qsw * 8;
    const unsigned short* Bp1 = Wt + (size_t)(n0 + (w + 8) * 16 + lrow) * 256 + qsw * 8;

    int aswz = (lg ^ ((lr >> 1) & 3)) * 8;

    f32x4 acc[2][8] = {};

    gll16(Apt, &sh[(w * 16) * 32]);
    gll16(Bp0, &sh[8192 + (w * 16) * 32]);
    gll16(Bp1, &sh[8192 + ((w + 8) * 16) * 32]);
    __syncthreads();

    int cur = 0;
    for (int step = 0; step < 8; ++step) {
        if (step < 7) {
            int k0 = (step + 1) * 32;
            int nbA = (cur ^ 1) * 4096;
            int nbB = 8192 + (cur ^ 1) * 8192;
            gll16(Apt + k0, &sh[nbA + (w * 16) * 32]);
            gll16(Bp0 + k0, &sh[nbB + (w * 16) * 32]);
            gll16(Bp1 + k0, &sh[nbB + ((w + 8) * 16) * 32]);
        }
        int cbA = cur * 4096;
        int cbB = 8192 + cur * 8192;
        short8 fa[2], fb[8];
        #pragma unroll
        for (int f = 0; f < 2; ++f)
            fa[f] = *(const short8*)&sh[cbA + (wr * 32 + f * 16 + lr) * 32 + aswz];
        #pragma unroll
        for (int f = 0; f < 8; ++f)
            fb[f] = *(const short8*)&sh[cbB + (wc * 128 + f * 16 + lr) * 32 + aswz];
        #pragma unroll
        for (int fr = 0; fr < 2; ++fr)
            #pragma unroll
            for (int fc = 0; fc < 8; ++fc)
                acc[fr][fc] = __builtin_amdgcn_mfma_f32_16x16x32_bf16(fa[fr], fb[fc], acc[fr][fc], 0, 0, 0);
        __syncthreads();
        cur ^= 1;
    }

    // ---- epilogue: stage acc (+bias) into 64KB LDS with granule swizzle ----
    #pragma unroll
    for (int fr = 0; fr < 2; ++fr) {
        #pragma unroll
        for (int fc = 0; fc < 8; ++fc) {
            int col = wc * 128 + fc * 16 + lr;
            float bv = bias[n0 + col];
            int g = col >> 3;
            #pragma unroll
            for (int ri = 0; ri < 4; ++ri) {
                int row = wr * 32 + fr * 16 + lg * 4 + ri;
                sh[row * 256 + ((g ^ (row & 31)) << 3) + (col & 7)] =
                    f2bf(acc[fr][fc][ri] + bv);
            }
        }
    }
    __syncthreads();
    // ---- coalesced 16B store-out: 128 rows x 32 granules, 8 per thread ----
    #pragma unroll
    for (int p = 0; p < 8; ++p) {
        int row = p * 16 + (t >> 5);
        int cg = t & 31;
        ushort8v v8 = *(const ushort8v*)&sh[row * 256 + ((cg ^ (row & 31)) << 3)];
        int grow = m0 + row;
        if (grow < M)
            *(ushort8v*)&C[(size_t)grow * Ncat + n0 + cg * 8] = v8;
    }
}

// ======================================================================
// Output GEMM + gate + LayerNorm, author and paper batched in one grid.
// ======================================================================
__global__ __launch_bounds__(512, 2) void gemm_ln2(
    const unsigned short* __restrict__ Aa, const unsigned short* __restrict__ Ap2,
    const unsigned short* __restrict__ WtFc,  // 512 rows: [Wfc0T | Wfc1T]
    const float* __restrict__ hA, const float* __restrict__ hP,
    const float* __restrict__ bfc, const float* __restrict__ gg,
    const float* __restrict__ bb, const float* __restrict__ res,
    float* __restrict__ out, int NA, int NP, int nbA)
{
    __shared__ unsigned short As[2][128 * 32];
    __shared__ unsigned short Bs[2][256 * 32];
    __shared__ float red_s[128][2], red_q[128][2];

    int bid = blockIdx.x;
    int isP = bid >= nbA;
    int m0 = (isP ? bid - nbA : bid) * 128;
    int M = isP ? NP : NA;
    const unsigned short* A = isP ? Ap2 : Aa;
    const float* hin = isP ? hP : hA;
    float* o = out + (isP ? (size_t)NA * 256 : 0);
    const unsigned short* Wt = WtFc + (isP ? (size_t)256 * 256 : 0);
    const float* bfcn = bfc + (isP ? 256 : 0);
    const float* gn = gg + (isP ? 256 : 0);
    const float* bn = bb + (isP ? 256 : 0);
    float alpha = 1.f / (1.f + __expf(-res[isP ? 1 : 0]));
    float beta = 1.f - alpha;

    int t = threadIdx.x, w = t >> 6, l = t & 63;
    int lr = l & 15, lg = l >> 4;
    int wr = w >> 1, wc = w & 1;

    int lrow = l >> 2, lq = l & 3;
    int qsw = lq ^ ((lrow >> 1) & 3);
    int ar = m0 + w * 16 + lrow; if (ar >= M) ar = M - 1;
    const unsigned short* Apt = A  + (size_t)ar * 256 + qsw * 8;
    const unsigned short* Bp0 = Wt + (size_t)(w * 16 + lrow) * 256 + qsw * 8;
    const unsigned short* Bp1 = Wt + (size_t)((w + 8) * 16 + lrow) * 256 + qsw * 8;

    int aswz = (lg ^ ((lr >> 1) & 3)) * 8;

    f32x4 acc[2][8] = {};

    gll16(Apt, &As[0][(w * 16) * 32]);
    gll16(Bp0, &Bs[0][(w * 16) * 32]);
    gll16(Bp1, &Bs[0][((w + 8) * 16) * 32]);
    __syncthreads();

    int cur = 0;
    for (int step = 0; step < 8; ++step) {
        if (step < 7) {
            int k0 = (step + 1) * 32;
            gll16(Apt + k0, &As[cur ^ 1][(w * 16) * 32]);
            gll16(Bp0 + k0, &Bs[cur ^ 1][(w * 16) * 32]);
            gll16(Bp1 + k0, &Bs[cur ^ 1][((w + 8) * 16) * 32]);
        }
        short8 fa[2], fb[8];
        #pragma unroll
        for (int f = 0; f < 2; ++f)
            fa[f] = *(const short8*)&As[cur][(wr * 32 + f * 16 + lr) * 32 + aswz];
        #pragma unroll
        for (int f = 0; f < 8; ++f)
            fb[f] = *(const short8*)&Bs[cur][(wc * 128 + f * 16 + lr) * 32 + aswz];
        #pragma unroll
        for (int fr = 0; fr < 2; ++fr)
            #pragma unroll
            for (int fc = 0; fc < 8; ++fc)
                acc[fr][fc] = __builtin_amdgcn_mfma_f32_16x16x32_bf16(fa[fr], fb[fc], acc[fr][fc], 0, 0, 0);
        __syncthreads();
        cur ^= 1;
    }

    #pragma unroll
    for (int fr = 0; fr < 2; ++fr) {
        #pragma unroll
        for (int ri = 0; ri < 4; ++ri) {
            int rloc = wr * 32 + fr * 16 + lg * 4 + ri;
            int row = m0 + rloc;
            int rowc = row < M ? row : M - 1;
            float ps = 0.f, pq = 0.f;
            #pragma unroll
            for (int fc = 0; fc < 8; ++fc) {
                int col = wc * 128 + fc * 16 + lr;
                float hp = alpha * (acc[fr][fc][ri] + bfcn[col])
                         + beta * hin[(size_t)rowc * 256 + col];
                acc[fr][fc][ri] = hp;
                ps += hp;
                pq += hp * hp;
            }
            #pragma unroll
            for (int m = 1; m < 16; m <<= 1) {
                ps += __shfl_xor(ps, m);
                pq += __shfl_xor(pq, m);
            }
            if (lr == 0) { red_s[rloc][wc] = ps; red_q[rloc][wc] = pq; }
        }
    }
    __syncthreads();
    #pragma unroll
    for (int fr = 0; fr < 2; ++fr) {
        #pragma unroll
        for (int ri = 0; ri < 4; ++ri) {
            int rloc = wr * 32 + fr * 16 + lg * 4 + ri;
            int row = m0 + rloc;
            float s = red_s[rloc][0] + red_s[rloc][1];
            float q = red_q[rloc][0] + red_q[rloc][1];
            float mu = s * (1.f / 256.f);
            float var = q * (1.f / 256.f) - mu * mu;
            float rstd = rsqrtf(var + 1e-5f);
            if (row < M) {
                #pragma unroll
                for (int fc = 0; fc < 8; ++fc) {
                    int col = wc * 128 + fc * 16 + lr;
                    o[(size_t)row * 256 + col] =
                        (acc[fr][fc][ri] - mu) * rstd * gn[col] + bn[col];
                }
            }
        }
    }
}

// ---------- batched CSR build over 3 edge lists ----------
__global__ void k_hist3(const int* __restrict__ d0, const int* __restrict__ d1,
                        const int* __restrict__ d2, int E0, int E1, int E2,
                        int nb0, int nb01, int P, int* __restrict__ cnt)
{
    int bid = blockIdx.x;
    const int* d; int E, eb, base;
    if (bid < nb0)       { d = d0; E = E0; eb = bid;        base = 0; }
    else if (bid < nb01) { d = d1; E = E1; eb = bid - nb0;  base = P; }
    else                 { d = d2; E = E2; eb = bid - nb01; base = 2 * P; }
    int e = eb * 256 + threadIdx.x;
    if (e < E) atomicAdd(&cnt[base + d[e]], 1);
}

__global__ __launch_bounds__(256) void k_scan1(
    const int* __restrict__ cnt, int* __restrict__ offs, int* __restrict__ blksum, int N)
{
    __shared__ int sm[256];
    int t = threadIdx.x, i = blockIdx.x * 256 + t;
    int x = (i < N) ? cnt[i] : 0;
    sm[t] = x; __syncthreads();
    int v = x;
    #pragma unroll
    for (int off = 1; off < 256; off <<= 1) {
        int y = (t >= off) ? sm[t - off] : 0;
        __syncthreads();
        v += y; sm[t] = v;
        __syncthreads();
    }
    if (i < N) offs[i] = v - x;
    if (t == 255) blksum[blockIdx.x] = v;
}

// per-segment exclusive scan of block sums (3 segments of nbseg entries)
__global__ __launch_bounds__(512) void k_scan2s(int* __restrict__ blksum, int nbseg) {
    __shared__ int sm[512];
    int t = threadIdx.x;
    int* bs = blksum + blockIdx.x * nbseg;
    int x = (t < nbseg) ? bs[t] : 0;
    sm[t] = x; __syncthreads();
    int v = x;
    #pragma unroll
    for (int off = 1; off < 512; off <<= 1) {
        int y = (t >= off) ? sm[t - off] : 0;
        __syncthreads();
        v += y; sm[t] = v;
        __syncthreads();
    }
    if (t < nbseg) bs[t] = v - x;
}

__global__ void k_scan3(int* __restrict__ offs, int* __restrict__ cursor,
                        const int* __restrict__ blksum, int N)
{
    int i = blockIdx.x * 256 + threadIdx.x;
    if (i < N) {
        int v = offs[i] + blksum[i >> 8];
        offs[i] = v;
        cursor[i] = v;
    }
}

__global__ void k_scatter3(const int* __restrict__ s0, const int* __restrict__ d0,
                           const int* __restrict__ s1, const int* __restrict__ d1,
                           const int* __restrict__ s2, const int* __restrict__ d2,
                           int E0, int E1, int E2, int nb0, int nb01, int P,
                           int* __restrict__ cursor, int* __restrict__ ssrc)
{
    int bid = blockIdx.x;
    const int* s; const int* d; int E, eb, bn, be;
    if (bid < nb0)       { s = s0; d = d0; E = E0; eb = bid;        bn = 0;     be = 0; }
    else if (bid < nb01) { s = s1; d = d1; E = E1; eb = bid - nb0;  bn = P;     be = E0; }
    else                 { s = s2; d = d2; E = E2; eb = bid - nb01; bn = 2 * P; be = E0 + E1; }
    int e = eb * 256 + threadIdx.x;
    if (e < E) {
        int pos = atomicAdd(&cursor[bn + d[e]], 1);
        ssrc[be + pos] = s[e];
    }
}

// ---------- segment softmax-aggregate: 2 edges/iteration, 16B loads ----------
__device__ __forceinline__ void seg_agg8(
    int base, int deg, const int* __restrict__ ssrc,
    const unsigned short* __restrict__ ke, int ks,
    const unsigned short* __restrict__ ve, int vs,
    const float* qf, float cw, int sl, int half,
    float* o)
{
    float den = 0.f;
    float acc[8] = {0.f,0.f,0.f,0.f,0.f,0.f,0.f,0.f};
    for (int i = 0; i < deg; i += 2) {
        int idx = i + half;
        if (idx < deg) {
            int s = ssrc[base + idx];
            ushort8v kv = *(const ushort8v*)(ke + (size_t)s * ks + sl * 8);
            float p = qf[0] * bf2f(kv[0]) + qf[1] * bf2f(kv[1])
                    + qf[2] * bf2f(kv[2]) + qf[3] * bf2f(kv[3])
                    + qf[4] * bf2f(kv[4]) + qf[5] * bf2f(kv[5])
                    + qf[6] * bf2f(kv[6]) + qf[7] * bf2f(kv[7]);
            p += __shfl_xor(p, 1);
            p += __shfl_xor(p, 2);
            float ex = __expf(p * cw);
            ushort8v vv = *(const ushort8v*)(ve + (size_t)s * vs + sl * 8);
            den += ex;
            #pragma unroll
            for (int j = 0; j < 8; ++j) acc[j] += ex * bf2f(vv[j]);
        }
    }
    den += __shfl_xor(den, 32);
    #pragma unroll
    for (int j = 0; j < 8; ++j) acc[j] += __shfl_xor(acc[j], 32);
    float r = den > 0.f ? 1.f / den : 0.f;
    #pragma unroll
    for (int j = 0; j < 8; ++j) o[j] = acc[j] * r;
}

// ---------- all three edge-type aggregations in one dispatch ----------
// nodes [0,NP): papers (e0 writes + e2 cites, 0.5*mean) ; [NP,NP+NA): authors (e1)
__global__ __launch_bounds__(256) void agg_all(
    const int* __restrict__ cnt, const int* __restrict__ offs,
    const int* __restrict__ ssrc, int P, int E0, int E1,
    const unsigned short* __restrict__ qkv_a,   // [NA][768]  q|k0|v0
    const unsigned short* __restrict__ qkv_p,   // [NP][1280] q|k1|v1|k2|v2
    const float* __restrict__ canon, float rsdk,
    unsigned short* __restrict__ agg_w, unsigned short* __restrict__ agg_wb,
    int NP, int NA)
{
    int wave = threadIdx.x >> 6, lane = threadIdx.x & 63;
    int sl = lane & 31, half = lane >> 5;
    int g = blockIdx.x * 4 + wave;
    int h = sl >> 2;
    if (g < NP) {
        const ushort8v* qrow = (const ushort8v*)(qkv_p + (size_t)g * 1280);
        ushort8v q8 = __builtin_nontemporal_load(qrow + sl);
        float qf[8];
        #pragma unroll
        for (int j = 0; j < 8; ++j) qf[j] = bf2f(q8[j]);
        float a[8], b[8];
        seg_agg8(offs[g], cnt[g], ssrc,
                 qkv_a + 256, 768, qkv_a + 512, 768,
                 qf, canon[h] * rsdk, sl, half, a);
        seg_agg8(offs[2 * P + g], cnt[2 * P + g], ssrc + (E0 + E1),
                 qkv_p + 768, 1280, qkv_p + 1024, 1280,
                 qf, canon[16 + h] * rsdk, sl, half, b);
        if (half == 0) {
            ushort8v o8;
            #pragma unroll
            for (int j = 0; j < 8; ++j) o8[j] = f2bf(0.5f * (a[j] + b[j]));
            *(ushort8v*)(agg_w + (size_t)g * 256 + sl * 8) = o8;
        }
    } else if (g < NP + NA) {
        int n = g - NP;
        const ushort8v* qrow = (const ushort8v*)(qkv_a + (size_t)n * 768);
        ushort8v q8 = __builtin_nontemporal_load(qrow + sl);
        float qf[8];
        #pragma unroll
        for (int j = 0; j < 8; ++j) qf[j] = bf2f(q8[j]);
        float a[8];
        seg_agg8(offs[P + n], cnt[P + n], ssrc + E0,
                 qkv_p + 256, 1280, qkv_p + 512, 1280,
                 qf, canon[8 + h] * rsdk, sl, half, a);
        if (half == 0) {
            ushort8v o8;
            #pragma unroll
            for (int j = 0; j < 8; ++j) o8[j] = f2bf(a[j]);
            *(ushort8v*)(agg_wb + (size_t)n * 256 + sl * 8) = o8;
        }
    }
}

// ---------- launch ----------
extern "C" void kernel_launch(void* const* d_in, const int* in_sizes, int n_in,
                              void* d_out, int out_size, void* d_ws, size_t ws_size,
                              hipStream_t stream)
{
    const float* h_a   = (const float*)d_in[0];
    const float* h_p   = (const float*)d_in[1];
    const int* w_src   = (const int*)d_in[2];
    const int* w_dst   = (const int*)d_in[3];
    const int* wb_src  = (const int*)d_in[4];
    const int* wb_dst  = (const int*)d_in[5];
    const int* c_src   = (const int*)d_in[6];
    const int* c_dst   = (const int*)d_in[7];
    const float* Wk    = (const float*)d_in[8];
    const float* bk    = (const float*)d_in[9];
    const float* Wq    = (const float*)d_in[10];
    const float* bq    = (const float*)d_in[11];
    const float* Wv    = (const float*)d_in[12];
    const float* bv    = (const float*)d_in[13];
    const float* Wfc   = (const float*)d_in[14];
    const float* bfc   = (const float*)d_in[15];
    const float* ln_g  = (const float*)d_in[16];
    const float* ln_b  = (const float*)d_in[17];
    const float* att_w = (const float*)d_in[18];
    const float* val_w = (const float*)d_in[19];
    const float* canon = (const float*)d_in[20];
    const float* res   = (const float*)d_in[21];

    const int NA = in_sizes[0] / 256;
    const int NP = in_sizes[1] / 256;
    const int E0 = in_sizes[2];
    const int E1 = in_sizes[4];
    const int E2 = in_sizes[6];
    const int Nmax = NA > NP ? NA : NP;
    const int P = ((Nmax + 255) / 256) * 256;
    const int nbseg = P / 256;
    const int Etot = E0 + E1 + E2;

    // workspace layout
    char* p = (char*)d_ws;
    auto alloc = [&](size_t bytes) -> char* {
        char* r = p;
        p += (bytes + 255) & ~(size_t)255;
        return r;
    };
    unsigned short* wt = (unsigned short*)alloc((size_t)10 * 65536 * 2);
    float* eff_b = (float*)alloc(6 * 256 * 4);
    float* bias_cat = (float*)alloc(2048 * 4);
    unsigned short* qkv_a = (unsigned short*)alloc((size_t)NA * 768 * 2);
    unsigned short* qkv_p = (unsigned short*)alloc((size_t)NP * 1280 * 2);
    unsigned short* agg_w  = (unsigned short*)alloc((size_t)NP * 256 * 2);
    unsigned short* agg_wb = (unsigned short*)alloc((size_t)NA * 256 * 2);
    int* cnt    = (int*)alloc((size_t)3 * P * 4);
    int* offs   = (int*)alloc((size_t)3 * P * 4);
    int* cursor = (int*)alloc((size_t)3 * P * 4);
    int* blksum = (int*)alloc((size_t)3 * nbseg * 4);
    int* ssrc   = (int*)alloc((size_t)Etot * 4);

    // bf16 feature copies carved from d_out (dead before gemm_ln2 writes)
    unsigned short* ha_bf = (unsigned short*)d_out;
    unsigned short* hp_bf = ha_bf + (size_t)NA * 256;

    const float rsdk = 0.17677669529663687f;  // 1/sqrt(32)

    // ---- prep ----
    build_eff_t<<<1536, 256, 0, stream>>>(Wk, Wv, att_w, val_w, wt);
    build_eff_bias<<<6, 256, 0, stream>>>(bk, bv, att_w, val_w, eff_b);
    build_bias_cat<<<8, 256, 0, stream>>>(bq, eff_b, bias_cat);
    transpose_cast4<<<256, 256, 0, stream>>>(Wq, Wfc, wt);
    cast_bf16_2<<<(NA * 64 + NP * 64 + 255) / 256, 256, 0, stream>>>(
        h_a, h_p, ha_bf, hp_bf, NA * 64, NP * 64);

    // ---- batched CSR build (inputs only) ----
    hipMemsetAsync(cnt, 0, (size_t)3 * P * 4, stream);
    int nb0 = (E0 + 255) / 256, nb1 = (E1 + 255) / 256, nb2 = (E2 + 255) / 256;
    k_hist3<<<nb0 + nb1 + nb2, 256, 0, stream>>>(w_dst, wb_dst, c_dst, E0, E1, E2,
                                                 nb0, nb0 + nb1, P, cnt);
    k_scan1<<<3 * nbseg, 256, 0, stream>>>(cnt, offs, blksum, 3 * P);
    k_scan2s<<<3, 512, 0, stream>>>(blksum, nbseg);
    k_scan3<<<3 * nbseg, 256, 0, stream>>>(offs, cursor, blksum, 3 * P);
    k_scatter3<<<nb0 + nb1 + nb2, 256, 0, stream>>>(w_src, w_dst, wb_src, wb_dst,
                                                    c_src, c_dst, E0, E1, E2,
                                                    nb0, nb0 + nb1, P, cursor, ssrc);

    // ---- projections (128x256 tile, 1D grid + XCD-chunk swizzle) ----
    int gA = (NA + 127) / 128, gP = (NP + 127) / 128;
    int nwgA = gA * 3, nwgP = gP * 5;
    gemm_cat<<<nwgA, 512, 0, stream>>>(ha_bf, wt, bias_cat, qkv_a, NA, 768, 3, nwgA);
    gemm_cat<<<nwgP, 512, 0, stream>>>(hp_bf, wt + (size_t)768 * 256,
                                       bias_cat + 768, qkv_p, NP, 1280, 5, nwgP);

    // ---- all aggregations ----
    agg_all<<<(NP + NA + 3) / 4, 256, 0, stream>>>(cnt, offs, ssrc, P, E0, E1,
                                                   qkv_a, qkv_p, canon, rsdk,
                                                   agg_w, agg_wb, NP, NA);

    // ---- output GEMM + gate + LayerNorm (both node types, one dispatch) ----
    gemm_ln2<<<gA + gP, 512, 0, stream>>>(agg_wb, agg_w, wt + (size_t)2048 * 256,
                                          h_a, h_p, bfc, ln_g, ln_b, res,
                                          (float*)d_out, NA, NP, gA);
}

// Round 17
// 757.133 us; speedup vs baseline: 1.0774x; 1.0774x over previous
//
#include <hip/hip_runtime.h>
#include <hip/hip_bf16.h>
#include <math.h>

using short8  = __attribute__((ext_vector_type(8))) short;
using ushort8v = __attribute__((ext_vector_type(8))) unsigned short;
using f32x4   = __attribute__((ext_vector_type(4))) float;

// ---------- helpers ----------
__device__ __forceinline__ float bf2f(unsigned short u) {
    return __uint_as_float(((unsigned int)u) << 16);
}
__device__ __forceinline__ unsigned short f2bf(float f) {
    unsigned int x = __float_as_uint(f);
    return (unsigned short)((x + 0x7fffu + ((x >> 16) & 1u)) >> 16);
}
// async global->LDS, 16B per lane; LDS dest is wave-uniform base + lane*16
__device__ __forceinline__ void gll16(const void* g, void* l) {
    __builtin_amdgcn_global_load_lds(
        (const __attribute__((address_space(1))) unsigned int*)g,
        (__attribute__((address_space(3))) unsigned int*)l, 16, 0, 0);
}

// ---------- fused per-edge-type projection weights, written transposed bf16 ----------
// wt slots (rows of [2560][256]): 0 Wq0 | 1 e0k | 2 e0v | 3 Wq1 | 4 e1k | 5 e1v
//                                 | 6 e2k | 7 e2v | 8 Wfc0 | 9 Wfc1
__global__ __launch_bounds__(256) void build_eff_t(
    const float* __restrict__ Wk, const float* __restrict__ Wv,
    const float* __restrict__ att_w, const float* __restrict__ val_w,
    unsigned short* __restrict__ wt)
{
    int gid = blockIdx.x;          // mat*256 + c
    int mat = gid >> 8, c = gid & 255;   // mat: e*2 + (0=k,1=v)
    int e = mat >> 1, which = mat & 1;
    int ts = (e == 0) ? 0 : 1;
    int h = c >> 5, j = c & 31;
    int k = threadIdx.x;
    const float* Wsrc = (which == 0 ? Wk : Wv) + ((size_t)ts * 256 + k) * 256 + h * 32;
    const float* aw = (which == 0 ? att_w : val_w) + (size_t)((e * 8 + h) * 32) * 32 + j;
    float s = 0.f;
    #pragma unroll
    for (int d = 0; d < 32; ++d) s += Wsrc[d] * aw[d * 32];
    int slot = mat < 2 ? mat + 1 : mat + 2;
    wt[((size_t)slot * 256 + c) * 256 + k] = f2bf(s);
}

__global__ void build_eff_bias(
    const float* __restrict__ bk, const float* __restrict__ bv,
    const float* __restrict__ att_w, const float* __restrict__ val_w,
    float* __restrict__ effb)
{
    int mat = blockIdx.x;          // 0..5
    int c = threadIdx.x;
    int e = mat >> 1, which = mat & 1;
    int ts = (e == 0) ? 0 : 1;
    int h = c >> 5, j = c & 31;
    const float* bsrc = (which == 0 ? bk : bv) + ts * 256 + h * 32;
    const float* aw = (which == 0 ? att_w : val_w) + (size_t)((e * 8 + h) * 32) * 32 + j;
    float s = 0.f;
    #pragma unroll
    for (int d = 0; d < 32; ++d) s += bsrc[d] * aw[d * 32];
    effb[mat * 256 + c] = s;
}

// bias_cat[2048]: [bq0|e0k|e0v]  [bq1|e1k|e1v|e2k|e2v]
__global__ void build_bias_cat(const float* __restrict__ bq,
                               const float* __restrict__ effb,
                               float* __restrict__ bc)
{
    int i = blockIdx.x * 256 + threadIdx.x;
    int seg = i >> 8, o = i & 255;
    float v;
    switch (seg) {
        case 0: v = bq[o]; break;
        case 1: v = effb[o]; break;
        case 2: v = effb[256 + o]; break;
        case 3: v = bq[256 + o]; break;
        case 4: v = effb[512 + o]; break;
        case 5: v = effb[768 + o]; break;
        case 6: v = effb[1024 + o]; break;
        default: v = effb[1280 + o]; break;
    }
    bc[i] = v;
}

// transpose+cast Wq0, Wq1, Wfc0, Wfc1 into wt slots 0,3,8,9
__global__ __launch_bounds__(256) void transpose_cast4(
    const float* __restrict__ Wq, const float* __restrict__ Wfc,
    unsigned short* __restrict__ wt)
{
    __shared__ float tile[32][33];
    int mi = blockIdx.x >> 6;
    int bid = blockIdx.x & 63;
    const float* src; int slot;
    switch (mi) {
        case 0: src = Wq;           slot = 0; break;
        case 1: src = Wq + 65536;   slot = 3; break;
        case 2: src = Wfc;          slot = 8; break;
        default: src = Wfc + 65536; slot = 9; break;
    }
    unsigned short* dst = wt + (size_t)slot * 65536;
    int bx = bid & 7, by = bid >> 3;
    int tx = threadIdx.x & 31, ty = threadIdx.x >> 5;
    #pragma unroll
    for (int i = 0; i < 4; ++i)
        tile[ty + i * 8][tx] = src[(size_t)(by * 32 + ty + i * 8) * 256 + bx * 32 + tx];
    __syncthreads();
    #pragma unroll
    for (int i = 0; i < 4; ++i)
        dst[(size_t)(bx * 32 + ty + i * 8) * 256 + by * 32 + tx] = f2bf(tile[tx][ty + i * 8]);
}

// cast both feature matrices in one dispatch
__global__ void cast_bf16_2(const float* __restrict__ a, const float* __restrict__ b,
                            unsigned short* __restrict__ oa, unsigned short* __restrict__ ob,
                            int n4a, int n4b)
{
    int i = blockIdx.x * 256 + threadIdx.x;
    if (i < n4a) {
        float4 v = ((const float4*)a)[i];
        ushort4 o; o.x = f2bf(v.x); o.y = f2bf(v.y); o.z = f2bf(v.z); o.w = f2bf(v.w);
        ((ushort4*)oa)[i] = o;
    } else if (i - n4a < n4b) {
        int j = i - n4a;
        float4 v = ((const float4*)b)[j];
        ushort4 o; o.x = f2bf(v.x); o.y = f2bf(v.y); o.z = f2bf(v.z); o.w = f2bf(v.w);
        ((ushort4*)ob)[j] = o;
    }
}

// ======================================================================
// Input-side GEMM: C[M][Ncat] = A[M][256](bf16) @ Wt_seg (+bias), tile 128x128,
// 256 thr / 4 waves, BK=32, dbuf global_load_lds(16B), both-sides XOR swizzle.
// 1D grid + bijective XCD-chunk swizzle (m204): col-siblings of one row-tile
// land on the SAME XCD -> shared A-tile L2-hits.
// Epilogue: acc -> LDS (swizzled, bank-safe) -> 16B-coalesced global stores.
// ======================================================================
__global__ __launch_bounds__(256, 4) void gemm_cat(
    const unsigned short* __restrict__ A, const unsigned short* __restrict__ Wt,
    const float* __restrict__ bias, unsigned short* __restrict__ C,
    int M, int Ncat, int ncols, int nwg)
{
    __shared__ unsigned short sh[16384];   // K-loop: As[2][4096] | Bs[2][4096]; epilogue: 128x128 stage
    int orig = blockIdx.x;
    int q = nwg >> 3, r = nwg & 7;
    int xcd = orig & 7;
    int wgid = (xcd < r ? xcd * (q + 1) : r * (q + 1) + (xcd - r) * q) + (orig >> 3);
    int m0 = (wgid / ncols) * 128;
    int n0 = (wgid % ncols) * 128;

    int t = threadIdx.x, w = t >> 6, l = t & 63;
    int lr = l & 15, lg = l >> 4;
    int wr = w >> 1, wc = w & 1;

    int lrow = l >> 2, lq = l & 3;
    int qsw = lq ^ ((lrow >> 1) & 3);
    int ar0 = m0 + w * 16 + lrow;        if (ar0 >= M) ar0 = M - 1;
    int ar1 = m0 + (w + 4) * 16 + lrow;  if (ar1 >= M) ar1 = M - 1;
    const unsigned short* Ap0 = A + (size_t)ar0 * 256 + qsw * 8;
    const unsigned short* Ap1 = A + (size_t)ar1 * 256 + qsw * 8;
    const unsigned short* Bp0 = Wt + (size_t)(n0 + w * 16 + lrow) * 256 + qsw * 8;
    const unsigned short* Bp1 = Wt + (size_t)(n0 + (w + 4) * 16 + lrow) * 256 + qsw * 8;

    int aswz = (lg ^ ((lr >> 1) & 3)) * 8;

    f32x4 acc[4][4] = {};

    gll16(Ap0, &sh[(w * 16) * 32]);
    gll16(Ap1, &sh[((w + 4) * 16) * 32]);
    gll16(Bp0, &sh[8192 + (w * 16) * 32]);
    gll16(Bp1, &sh[8192 + ((w + 4) * 16) * 32]);
    __syncthreads();

    int cur = 0;
    for (int step = 0; step < 8; ++step) {
        if (step < 7) {
            int k0 = (step + 1) * 32;
            int nb = (cur ^ 1) * 4096;
            gll16(Ap0 + k0, &sh[nb + (w * 16) * 32]);
            gll16(Ap1 + k0, &sh[nb + ((w + 4) * 16) * 32]);
            gll16(Bp0 + k0, &sh[8192 + nb + (w * 16) * 32]);
            gll16(Bp1 + k0, &sh[8192 + nb + ((w + 4) * 16) * 32]);
        }
        int cb = cur * 4096;
        short8 fa[4], fb[4];
        #pragma unroll
        for (int f = 0; f < 4; ++f) {
            fa[f] = *(const short8*)&sh[cb + (wr * 64 + f * 16 + lr) * 32 + aswz];
            fb[f] = *(const short8*)&sh[8192 + cb + (wc * 64 + f * 16 + lr) * 32 + aswz];
        }
        #pragma unroll
        for (int fr = 0; fr < 4; ++fr)
            #pragma unroll
            for (int fc = 0; fc < 4; ++fc)
                acc[fr][fc] = __builtin_amdgcn_mfma_f32_16x16x32_bf16(fa[fr], fb[fc], acc[fr][fc], 0, 0, 0);
        __syncthreads();
        cur ^= 1;
    }

    // ---- epilogue: stage acc (+bias) into LDS with granule swizzle ----
    #pragma unroll
    for (int fr = 0; fr < 4; ++fr) {
        #pragma unroll
        for (int fc = 0; fc < 4; ++fc) {
            int col = wc * 64 + fc * 16 + lr;
            float bv = bias[n0 + col];
            #pragma unroll
            for (int ri = 0; ri < 4; ++ri) {
                int row = wr * 64 + fr * 16 + lg * 4 + ri;
                sh[row * 128 + (((col >> 3) ^ (row & 15)) << 3) + (col & 7)] =
                    f2bf(acc[fr][fc][ri] + bv);
            }
        }
    }
    __syncthreads();
    // ---- coalesced 16B store-out ----
    #pragma unroll
    for (int p = 0; p < 8; ++p) {
        int row = p * 16 + (t >> 4);
        int cg = t & 15;
        ushort8v v8 = *(const ushort8v*)&sh[row * 128 + ((cg ^ (row & 15)) << 3)];
        int grow = m0 + row;
        if (grow < M)
            *(ushort8v*)&C[(size_t)grow * Ncat + n0 + cg * 8] = v8;
    }
}

// ======================================================================
// Output GEMM + gate + LayerNorm, author and paper batched in one grid.
// ======================================================================
__global__ __launch_bounds__(512, 2) void gemm_ln2(
    const unsigned short* __restrict__ Aa, const unsigned short* __restrict__ Ap2,
    const unsigned short* __restrict__ WtFc,  // 512 rows: [Wfc0T | Wfc1T]
    const float* __restrict__ hA, const float* __restrict__ hP,
    const float* __restrict__ bfc, const float* __restrict__ gg,
    const float* __restrict__ bb, const float* __restrict__ res,
    float* __restrict__ out, int NA, int NP, int nbA)
{
    __shared__ unsigned short As[2][128 * 32];
    __shared__ unsigned short Bs[2][256 * 32];
    __shared__ float red_s[128][2], red_q[128][2];

    int bid = blockIdx.x;
    int isP = bid >= nbA;
    int m0 = (isP ? bid - nbA : bid) * 128;
    int M = isP ? NP : NA;
    const unsigned short* A = isP ? Ap2 : Aa;
    const float* hin = isP ? hP : hA;
    float* o = out + (isP ? (size_t)NA * 256 : 0);
    const unsigned short* Wt = WtFc + (isP ? (size_t)256 * 256 : 0);
    const float* bfcn = bfc + (isP ? 256 : 0);
    const float* gn = gg + (isP ? 256 : 0);
    const float* bn = bb + (isP ? 256 : 0);
    float alpha = 1.f / (1.f + __expf(-res[isP ? 1 : 0]));
    float beta = 1.f - alpha;

    int t = threadIdx.x, w = t >> 6, l = t & 63;
    int lr = l & 15, lg = l >> 4;
    int wr = w >> 1, wc = w & 1;

    int lrow = l >> 2, lq = l & 3;
    int qsw = lq ^ ((lrow >> 1) & 3);
    int ar = m0 + w * 16 + lrow; if (ar >= M) ar = M - 1;
    const unsigned short* Apt = A  + (size_t)ar * 256 + qsw * 8;
    const unsigned short* Bp0 = Wt + (size_t)(w * 16 + lrow) * 256 + qsw * 8;
    const unsigned short* Bp1 = Wt + (size_t)((w + 8) * 16 + lrow) * 256 + qsw * 8;

    int aswz = (lg ^ ((lr >> 1) & 3)) * 8;

    f32x4 acc[2][8] = {};

    gll16(Apt, &As[0][(w * 16) * 32]);
    gll16(Bp0, &Bs[0][(w * 16) * 32]);
    gll16(Bp1, &Bs[0][((w + 8) * 16) * 32]);
    __syncthreads();

    int cur = 0;
    for (int step = 0; step < 8; ++step) {
        if (step < 7) {
            int k0 = (step + 1) * 32;
            gll16(Apt + k0, &As[cur ^ 1][(w * 16) * 32]);
            gll16(Bp0 + k0, &Bs[cur ^ 1][(w * 16) * 32]);
            gll16(Bp1 + k0, &Bs[cur ^ 1][((w + 8) * 16) * 32]);
        }
        short8 fa[2], fb[8];
        #pragma unroll
        for (int f = 0; f < 2; ++f)
            fa[f] = *(const short8*)&As[cur][(wr * 32 + f * 16 + lr) * 32 + aswz];
        #pragma unroll
        for (int f = 0; f < 8; ++f)
            fb[f] = *(const short8*)&Bs[cur][(wc * 128 + f * 16 + lr) * 32 + aswz];
        #pragma unroll
        for (int fr = 0; fr < 2; ++fr)
            #pragma unroll
            for (int fc = 0; fc < 8; ++fc)
                acc[fr][fc] = __builtin_amdgcn_mfma_f32_16x16x32_bf16(fa[fr], fb[fc], acc[fr][fc], 0, 0, 0);
        __syncthreads();
        cur ^= 1;
    }

    #pragma unroll
    for (int fr = 0; fr < 2; ++fr) {
        #pragma unroll
        for (int ri = 0; ri < 4; ++ri) {
            int rloc = wr * 32 + fr * 16 + lg * 4 + ri;
            int row = m0 + rloc;
            int rowc = row < M ? row : M - 1;
            float ps = 0.f, pq = 0.f;
            #pragma unroll
            for (int fc = 0; fc < 8; ++fc) {
                int col = wc * 128 + fc * 16 + lr;
                float hp = alpha * (acc[fr][fc][ri] + bfcn[col])
                         + beta * hin[(size_t)rowc * 256 + col];
                acc[fr][fc][ri] = hp;
                ps += hp;
                pq += hp * hp;
            }
            #pragma unroll
            for (int m = 1; m < 16; m <<= 1) {
                ps += __shfl_xor(ps, m);
                pq += __shfl_xor(pq, m);
            }
            if (lr == 0) { red_s[rloc][wc] = ps; red_q[rloc][wc] = pq; }
        }
    }
    __syncthreads();
    #pragma unroll
    for (int fr = 0; fr < 2; ++fr) {
        #pragma unroll
        for (int ri = 0; ri < 4; ++ri) {
            int rloc = wr * 32 + fr * 16 + lg * 4 + ri;
            int row = m0 + rloc;
            float s = red_s[rloc][0] + red_s[rloc][1];
            float q = red_q[rloc][0] + red_q[rloc][1];
            float mu = s * (1.f / 256.f);
            float var = q * (1.f / 256.f) - mu * mu;
            float rstd = rsqrtf(var + 1e-5f);
            if (row < M) {
                #pragma unroll
                for (int fc = 0; fc < 8; ++fc) {
                    int col = wc * 128 + fc * 16 + lr;
                    o[(size_t)row * 256 + col] =
                        (acc[fr][fc][ri] - mu) * rstd * gn[col] + bn[col];
                }
            }
        }
    }
}

// ---------- batched CSR build over 3 edge lists ----------
__global__ void k_hist3(const int* __restrict__ d0, const int* __restrict__ d1,
                        const int* __restrict__ d2, int E0, int E1, int E2,
                        int nb0, int nb01, int P, int* __restrict__ cnt)
{
    int bid = blockIdx.x;
    const int* d; int E, eb, base;
    if (bid < nb0)       { d = d0; E = E0; eb = bid;        base = 0; }
    else if (bid < nb01) { d = d1; E = E1; eb = bid - nb0;  base = P; }
    else                 { d = d2; E = E2; eb = bid - nb01; base = 2 * P; }
    int e = eb * 256 + threadIdx.x;
    if (e < E) atomicAdd(&cnt[base + d[e]], 1);
}

__global__ __launch_bounds__(256) void k_scan1(
    const int* __restrict__ cnt, int* __restrict__ offs, int* __restrict__ blksum, int N)
{
    __shared__ int sm[256];
    int t = threadIdx.x, i = blockIdx.x * 256 + t;
    int x = (i < N) ? cnt[i] : 0;
    sm[t] = x; __syncthreads();
    int v = x;
    #pragma unroll
    for (int off = 1; off < 256; off <<= 1) {
        int y = (t >= off) ? sm[t - off] : 0;
        __syncthreads();
        v += y; sm[t] = v;
        __syncthreads();
    }
    if (i < N) offs[i] = v - x;
    if (t == 255) blksum[blockIdx.x] = v;
}

// per-segment exclusive scan of block sums (3 segments of nbseg entries)
__global__ __launch_bounds__(512) void k_scan2s(int* __restrict__ blksum, int nbseg) {
    __shared__ int sm[512];
    int t = threadIdx.x;
    int* bs = blksum + blockIdx.x * nbseg;
    int x = (t < nbseg) ? bs[t] : 0;
    sm[t] = x; __syncthreads();
    int v = x;
    #pragma unroll
    for (int off = 1; off < 512; off <<= 1) {
        int y = (t >= off) ? sm[t - off] : 0;
        __syncthreads();
        v += y; sm[t] = v;
        __syncthreads();
    }
    if (t < nbseg) bs[t] = v - x;
}

__global__ void k_scan3(int* __restrict__ offs, int* __restrict__ cursor,
                        const int* __restrict__ blksum, int N)
{
    int i = blockIdx.x * 256 + threadIdx.x;
    if (i < N) {
        int v = offs[i] + blksum[i >> 8];
        offs[i] = v;
        cursor[i] = v;
    }
}

__global__ void k_scatter3(const int* __restrict__ s0, const int* __restrict__ d0,
                           const int* __restrict__ s1, const int* __restrict__ d1,
                           const int* __restrict__ s2, const int* __restrict__ d2,
                           int E0, int E1, int E2, int nb0, int nb01, int P,
                           int* __restrict__ cursor, int* __restrict__ ssrc)
{
    int bid = blockIdx.x;
    const int* s; const int* d; int E, eb, bn, be;
    if (bid < nb0)       { s = s0; d = d0; E = E0; eb = bid;        bn = 0;     be = 0; }
    else if (bid < nb01) { s = s1; d = d1; E = E1; eb = bid - nb0;  bn = P;     be = E0; }
    else                 { s = s2; d = d2; E = E2; eb = bid - nb01; bn = 2 * P; be = E0 + E1; }
    int e = eb * 256 + threadIdx.x;
    if (e < E) {
        int pos = atomicAdd(&cursor[bn + d[e]], 1);
        ssrc[be + pos] = s[e];
    }
}

// ---------- segment softmax-aggregate: 2 edges/iteration, 16B loads ----------
__device__ __forceinline__ void seg_agg8(
    int base, int deg, const int* __restrict__ ssrc,
    const unsigned short* __restrict__ ke, int ks,
    const unsigned short* __restrict__ ve, int vs,
    const float* qf, float cw, int sl, int half,
    float* o)
{
    float den = 0.f;
    float acc[8] = {0.f,0.f,0.f,0.f,0.f,0.f,0.f,0.f};
    for (int i = 0; i < deg; i += 2) {
        int idx = i + half;
        if (idx < deg) {
            int s = ssrc[base + idx];
            ushort8v kv = *(const ushort8v*)(ke + (size_t)s * ks + sl * 8);
            float p = qf[0] * bf2f(kv[0]) + qf[1] * bf2f(kv[1])
                    + qf[2] * bf2f(kv[2]) + qf[3] * bf2f(kv[3])
                    + qf[4] * bf2f(kv[4]) + qf[5] * bf2f(kv[5])
                    + qf[6] * bf2f(kv[6]) + qf[7] * bf2f(kv[7]);
            p += __shfl_xor(p, 1);
            p += __shfl_xor(p, 2);
            float ex = __expf(p * cw);
            ushort8v vv = *(const ushort8v*)(ve + (size_t)s * vs + sl * 8);
            den += ex;
            #pragma unroll
            for (int j = 0; j < 8; ++j) acc[j] += ex * bf2f(vv[j]);
        }
    }
    den += __shfl_xor(den, 32);
    #pragma unroll
    for (int j = 0; j < 8; ++j) acc[j] += __shfl_xor(acc[j], 32);
    float r = den > 0.f ? 1.f / den : 0.f;
    #pragma unroll
    for (int j = 0; j < 8; ++j) o[j] = acc[j] * r;
}

// ---------- all three edge-type aggregations in one dispatch ----------
// nodes [0,NP): papers (e0 writes + e2 cites, 0.5*mean) ; [NP,NP+NA): authors (e1)
__global__ __launch_bounds__(256) void agg_all(
    const int* __restrict__ cnt, const int* __restrict__ offs,
    const int* __restrict__ ssrc, int P, int E0, int E1,
    const unsigned short* __restrict__ qkv_a,   // [NA][768]  q|k0|v0
    const unsigned short* __restrict__ qkv_p,   // [NP][1280] q|k1|v1|k2|v2
    const float* __restrict__ canon, float rsdk,
    unsigned short* __restrict__ agg_w, unsigned short* __restrict__ agg_wb,
    int NP, int NA)
{
    int wave = threadIdx.x >> 6, lane = threadIdx.x & 63;
    int sl = lane & 31, half = lane >> 5;
    int g = blockIdx.x * 4 + wave;
    int h = sl >> 2;
    if (g < NP) {
        const ushort8v* qrow = (const ushort8v*)(qkv_p + (size_t)g * 1280);
        ushort8v q8 = __builtin_nontemporal_load(qrow + sl);
        float qf[8];
        #pragma unroll
        for (int j = 0; j < 8; ++j) qf[j] = bf2f(q8[j]);
        float a[8], b[8];
        seg_agg8(offs[g], cnt[g], ssrc,
                 qkv_a + 256, 768, qkv_a + 512, 768,
                 qf, canon[h] * rsdk, sl, half, a);
        seg_agg8(offs[2 * P + g], cnt[2 * P + g], ssrc + (E0 + E1),
                 qkv_p + 768, 1280, qkv_p + 1024, 1280,
                 qf, canon[16 + h] * rsdk, sl, half, b);
        if (half == 0) {
            ushort8v o8;
            #pragma unroll
            for (int j = 0; j < 8; ++j) o8[j] = f2bf(0.5f * (a[j] + b[j]));
            *(ushort8v*)(agg_w + (size_t)g * 256 + sl * 8) = o8;
        }
    } else if (g < NP + NA) {
        int n = g - NP;
        const ushort8v* qrow = (const ushort8v*)(qkv_a + (size_t)n * 768);
        ushort8v q8 = __builtin_nontemporal_load(qrow + sl);
        float qf[8];
        #pragma unroll
        for (int j = 0; j < 8; ++j) qf[j] = bf2f(q8[j]);
        float a[8];
        seg_agg8(offs[P + n], cnt[P + n], ssrc + E0,
                 qkv_p + 256, 1280, qkv_p + 512, 1280,
                 qf, canon[8 + h] * rsdk, sl, half, a);
        if (half == 0) {
            ushort8v o8;
            #pragma unroll
            for (int j = 0; j < 8; ++j) o8[j] = f2bf(a[j]);
            *(ushort8v*)(agg_wb + (size_t)n * 256 + sl * 8) = o8;
        }
    }
}

// ---------- launch ----------
extern "C" void kernel_launch(void* const* d_in, const int* in_sizes, int n_in,
                              void* d_out, int out_size, void* d_ws, size_t ws_size,
                              hipStream_t stream)
{
    const float* h_a   = (const float*)d_in[0];
    const float* h_p   = (const float*)d_in[1];
    const int* w_src   = (const int*)d_in[2];
    const int* w_dst   = (const int*)d_in[3];
    const int* wb_src  = (const int*)d_in[4];
    const int* wb_dst  = (const int*)d_in[5];
    const int* c_src   = (const int*)d_in[6];
    const int* c_dst   = (const int*)d_in[7];
    const float* Wk    = (const float*)d_in[8];
    const float* bk    = (const float*)d_in[9];
    const float* Wq    = (const float*)d_in[10];
    const float* bq    = (const float*)d_in[11];
    const float* Wv    = (const float*)d_in[12];
    const float* bv    = (const float*)d_in[13];
    const float* Wfc   = (const float*)d_in[14];
    const float* bfc   = (const float*)d_in[15];
    const float* ln_g  = (const float*)d_in[16];
    const float* ln_b  = (const float*)d_in[17];
    const float* att_w = (const float*)d_in[18];
    const float* val_w = (const float*)d_in[19];
    const float* canon = (const float*)d_in[20];
    const float* res   = (const float*)d_in[21];

    const int NA = in_sizes[0] / 256;
    const int NP = in_sizes[1] / 256;
    const int E0 = in_sizes[2];
    const int E1 = in_sizes[4];
    const int E2 = in_sizes[6];
    const int Nmax = NA > NP ? NA : NP;
    const int P = ((Nmax + 255) / 256) * 256;
    const int nbseg = P / 256;
    const int Etot = E0 + E1 + E2;

    // workspace layout
    char* p = (char*)d_ws;
    auto alloc = [&](size_t bytes) -> char* {
        char* r = p;
        p += (bytes + 255) & ~(size_t)255;
        return r;
    };
    unsigned short* wt = (unsigned short*)alloc((size_t)10 * 65536 * 2);
    float* eff_b = (float*)alloc(6 * 256 * 4);
    float* bias_cat = (float*)alloc(2048 * 4);
    unsigned short* qkv_a = (unsigned short*)alloc((size_t)NA * 768 * 2);
    unsigned short* qkv_p = (unsigned short*)alloc((size_t)NP * 1280 * 2);
    unsigned short* agg_w  = (unsigned short*)alloc((size_t)NP * 256 * 2);
    unsigned short* agg_wb = (unsigned short*)alloc((size_t)NA * 256 * 2);
    int* cnt    = (int*)alloc((size_t)3 * P * 4);
    int* offs   = (int*)alloc((size_t)3 * P * 4);
    int* cursor = (int*)alloc((size_t)3 * P * 4);
    int* blksum = (int*)alloc((size_t)3 * nbseg * 4);
    int* ssrc   = (int*)alloc((size_t)Etot * 4);

    // bf16 feature copies carved from d_out (dead before gemm_ln2 writes)
    unsigned short* ha_bf = (unsigned short*)d_out;
    unsigned short* hp_bf = ha_bf + (size_t)NA * 256;

    const float rsdk = 0.17677669529663687f;  // 1/sqrt(32)

    // ---- prep ----
    build_eff_t<<<1536, 256, 0, stream>>>(Wk, Wv, att_w, val_w, wt);
    build_eff_bias<<<6, 256, 0, stream>>>(bk, bv, att_w, val_w, eff_b);
    build_bias_cat<<<8, 256, 0, stream>>>(bq, eff_b, bias_cat);
    transpose_cast4<<<256, 256, 0, stream>>>(Wq, Wfc, wt);
    cast_bf16_2<<<(NA * 64 + NP * 64 + 255) / 256, 256, 0, stream>>>(
        h_a, h_p, ha_bf, hp_bf, NA * 64, NP * 64);

    // ---- batched CSR build (inputs only) ----
    hipMemsetAsync(cnt, 0, (size_t)3 * P * 4, stream);
    int nb0 = (E0 + 255) / 256, nb1 = (E1 + 255) / 256, nb2 = (E2 + 255) / 256;
    k_hist3<<<nb0 + nb1 + nb2, 256, 0, stream>>>(w_dst, wb_dst, c_dst, E0, E1, E2,
                                                 nb0, nb0 + nb1, P, cnt);
    k_scan1<<<3 * nbseg, 256, 0, stream>>>(cnt, offs, blksum, 3 * P);
    k_scan2s<<<3, 512, 0, stream>>>(blksum, nbseg);
    k_scan3<<<3 * nbseg, 256, 0, stream>>>(offs, cursor, blksum, 3 * P);
    k_scatter3<<<nb0 + nb1 + nb2, 256, 0, stream>>>(w_src, w_dst, wb_src, wb_dst,
                                                    c_src, c_dst, E0, E1, E2,
                                                    nb0, nb0 + nb1, P, cursor, ssrc);

    // ---- projections (1D grid + XCD-chunk swizzle for A-tile L2 reuse) ----
    int gA = (NA + 127) / 128, gP = (NP + 127) / 128;
    int nwgA = gA * 6, nwgP = gP * 10;
    gemm_cat<<<nwgA, 256, 0, stream>>>(ha_bf, wt, bias_cat, qkv_a, NA, 768, 6, nwgA);
    gemm_cat<<<nwgP, 256, 0, stream>>>(hp_bf, wt + (size_t)768 * 256,
                                       bias_cat + 768, qkv_p, NP, 1280, 10, nwgP);

    // ---- all aggregations ----
    agg_all<<<(NP + NA + 3) / 4, 256, 0, stream>>>(cnt, offs, ssrc, P, E0, E1,
                                                   qkv_a, qkv_p, canon, rsdk,
                                                   agg_w, agg_wb, NP, NA);

    // ---- output GEMM + gate + LayerNorm (both node types, one dispatch) ----
    gemm_ln2<<<gA + gP, 512, 0, stream>>>(agg_wb, agg_w, wt + (size_t)2048 * 256,
                                          h_a, h_p, bfc, ln_g, ln_b, res,
                                          (float*)d_out, NA, NP, gA);
}